// Round 9
// baseline (70.279 us; speedup 1.0000x reference)
//
#include <hip/hip_runtime.h>
#include <hip/hip_bf16.h>

typedef __bf16 bf16x8 __attribute__((ext_vector_type(8)));
typedef float f32x4 __attribute__((ext_vector_type(4)));

#define HDIM 4096
#define EDIM 64
#define KBLK 128        // 4096 / 32
#define NW 8            // waves per block = K-split factor
#define KBW (KBLK/NW)   // 16 kb-steps per wave
#define NRG 4           // row-groups per wave (64 rows per block)

// ---------------------------------------------------------------------------
// Kernel 1: coalesced repack of W into MFMA B-frag layout (UNnormalized bf16)
// + per-block per-column sum-of-squares partials (fp32).
// Wp element index for B[k][e]: nt=e>>4, col=e&15, kb=k>>5, g=(k>>3)&3, j=k&7
//   -> ((nt*KBLK + kb)*64 + col + 16*g)*8 + j
// ---------------------------------------------------------------------------
__global__ __launch_bounds__(256) void pack_w_kernel(const float* __restrict__ W,
                                                     __bf16* __restrict__ Wp,
                                                     float* __restrict__ partial) {
  const int b = blockIdx.x;        // 64 blocks x 64 rows of W
  const int t = threadIdx.x;
  const int e = t & 63;
  const int nt = e >> 4, col = e & 15;
  __shared__ float red[256];
  float s = 0.f;
  const int base = b * 64 * 64;
#pragma unroll
  for (int i = 0; i < 16; ++i) {
    int flat = base + i * 256 + t;         // coalesced
    float v = W[flat];
    s = fmaf(v, v, s);
    int r = flat >> 6;                     // k index
    int kb = r >> 5, g = (r >> 3) & 3, j = r & 7;
    Wp[(size_t)((nt * KBLK + kb) * 64 + col + 16 * g) * 8 + j] = (__bf16)v;
  }
  red[t] = s;
  __syncthreads();
  if (t < 64)
    partial[b * 64 + t] = red[t] + red[t + 64] + red[t + 128] + red[t + 192];
}

// ---------------------------------------------------------------------------
// Kernel 2: fused norm_h @ (Wp * invw) + epilogue.
// R6 structure (64 rows/block, grid 256 = 1 block/CU, 8-wave K-split x8,
// direct global->reg A, no main-loop barriers) + NONTEMPORAL hints:
// H loads and out stores are streaming (read/written exactly once) -> keep
// them from evicting the L2-resident 512 KB packed B that every block
// re-reads. B loads stay cached.
// A-frag: lane l holds h[rg*16+(l&15)][kb*32+(l>>4)*8+j]  (fp32->bf16).
// C/D layout (m89): lane l, reg r -> row (l>>4)*4+r, col l&15.
// ---------------------------------------------------------------------------
__global__ __launch_bounds__(512, 1) void gate_main_kernel(
    const float* __restrict__ H, const __bf16* __restrict__ Wp,
    const float* __restrict__ G, const float* __restrict__ partial,
    float* __restrict__ out, size_t third) {
  const int lane = threadIdx.x & 63;
  const int w = threadIdx.x >> 6;        // wave id = K-slice id, 0..7
  const int m = lane & 15;
  const int g = lane >> 4;
  const int row0 = blockIdx.x * 64;

  __shared__ float lds_acc[NRG][4][4][NW][64];  // rg, nt, reg, slice, lane: 128 KB
  __shared__ float lds_ssq[NW][64];             // slice, row
  __shared__ float lds_invw[64];

  // W-column inv-norms from pack partials (tiny, once per block)
  if (threadIdx.x < 64) {
    float cs = 0.f;
#pragma unroll 8
    for (int i = 0; i < 64; ++i) cs += partial[i * 64 + threadIdx.x];
    lds_invw[threadIdx.x] = 1.0f / fmaxf(sqrtf(cs), 1e-12f);
  }

  const int kb0 = w * KBW;
  const float* hp0 = H + (size_t)(row0 + 0 * 16 + m) * HDIM + kb0 * 32 + g * 8;
  const float* hp1 = hp0 + (size_t)16 * HDIM;
  const float* hp2 = hp0 + (size_t)32 * HDIM;
  const float* hp3 = hp0 + (size_t)48 * HDIM;
  const bf16x8* bbase = reinterpret_cast<const bf16x8*>(Wp) + lane;

  f32x4 acc[NRG][4] = {};
  float ssqa[NRG], ssqb[NRG];
#pragma unroll
  for (int rg = 0; rg < NRG; ++rg) { ssqa[rg] = 0.f; ssqb[rg] = 0.f; }

#pragma unroll 2
  for (int i = 0; i < KBW; ++i) {
    f32x4 a0[NRG], a1[NRG];
    a0[0] = __builtin_nontemporal_load((const f32x4*)(hp0 + (size_t)i * 32));
    a1[0] = __builtin_nontemporal_load((const f32x4*)(hp0 + (size_t)i * 32 + 4));
    a0[1] = __builtin_nontemporal_load((const f32x4*)(hp1 + (size_t)i * 32));
    a1[1] = __builtin_nontemporal_load((const f32x4*)(hp1 + (size_t)i * 32 + 4));
    a0[2] = __builtin_nontemporal_load((const f32x4*)(hp2 + (size_t)i * 32));
    a1[2] = __builtin_nontemporal_load((const f32x4*)(hp2 + (size_t)i * 32 + 4));
    a0[3] = __builtin_nontemporal_load((const f32x4*)(hp3 + (size_t)i * 32));
    a1[3] = __builtin_nontemporal_load((const f32x4*)(hp3 + (size_t)i * 32 + 4));

    bf16x8 bfr[4];
#pragma unroll
    for (int nt = 0; nt < 4; ++nt)
      bfr[nt] = bbase[(size_t)(nt * KBLK + kb0 + i) * 64];

#pragma unroll
    for (int rg = 0; rg < NRG; ++rg) {
      bf16x8 af;
      af[0] = (__bf16)a0[rg][0]; af[1] = (__bf16)a0[rg][1];
      af[2] = (__bf16)a0[rg][2]; af[3] = (__bf16)a0[rg][3];
      af[4] = (__bf16)a1[rg][0]; af[5] = (__bf16)a1[rg][1];
      af[6] = (__bf16)a1[rg][2]; af[7] = (__bf16)a1[rg][3];

      ssqa[rg] = fmaf(a0[rg][0], a0[rg][0], ssqa[rg]);
      ssqb[rg] = fmaf(a0[rg][1], a0[rg][1], ssqb[rg]);
      ssqa[rg] = fmaf(a0[rg][2], a0[rg][2], ssqa[rg]);
      ssqb[rg] = fmaf(a0[rg][3], a0[rg][3], ssqb[rg]);
      ssqa[rg] = fmaf(a1[rg][0], a1[rg][0], ssqa[rg]);
      ssqb[rg] = fmaf(a1[rg][1], a1[rg][1], ssqb[rg]);
      ssqa[rg] = fmaf(a1[rg][2], a1[rg][2], ssqa[rg]);
      ssqb[rg] = fmaf(a1[rg][3], a1[rg][3], ssqb[rg]);

#pragma unroll
      for (int nt = 0; nt < 4; ++nt)
        acc[rg][nt] = __builtin_amdgcn_mfma_f32_16x16x32_bf16(af, bfr[nt], acc[rg][nt], 0, 0, 0);
    }
  }

  // per-row partial ssq for this K-slice; write acc partials to LDS
#pragma unroll
  for (int rg = 0; rg < NRG; ++rg) {
    float ssq = ssqa[rg] + ssqb[rg];
    ssq += __shfl_xor(ssq, 16, 64);
    ssq += __shfl_xor(ssq, 32, 64);
    if (g == 0) lds_ssq[w][rg * 16 + m] = ssq;
#pragma unroll
    for (int nt = 0; nt < 4; ++nt)
#pragma unroll
      for (int r = 0; r < 4; ++r)
        lds_acc[rg][nt][r][w][lane] = acc[rg][nt][r];
  }
  __syncthreads();

  // Epilogue: lane = output column e; wave w handles rows {8w .. 8w+7},
  // full 256-B contiguous nontemporal stores per output tensor.
  {
    const int e = lane;
    const float invw = lds_invw[e];
    const float sg = 1.0f / (1.0f + __expf(-G[e]));
    const int nt = e >> 4;
#pragma unroll
    for (int rr = 0; rr < 8; ++rr) {
      const int R = w * 8 + rr;
      const int rg = R >> 4;
      const int r = R & 3;
      const int lsrc = (((R >> 2) & 3) << 4) | (e & 15);
      float st = 0.f, a = 0.f;
#pragma unroll
      for (int s = 0; s < NW; ++s) {
        st += lds_ssq[s][R];
        a += lds_acc[rg][nt][r][s][lsrc];
      }
      float invh = 1.0f / fmaxf(sqrtf(st), 1e-12f);
      float raw = a * invh * invw;
      float sig = 1.0f / (1.0f + __expf(-raw));
      size_t idx = (size_t)(row0 + R) * EDIM + e;
      __builtin_nontemporal_store(raw, &out[idx]);
      __builtin_nontemporal_store(sig, &out[idx + third]);
      __builtin_nontemporal_store(fmaxf(sig - sg, 0.0f), &out[idx + 2 * third]);
    }
  }
}

extern "C" void kernel_launch(void* const* d_in, const int* in_sizes, int n_in,
                              void* d_out, int out_size, void* d_ws, size_t ws_size,
                              hipStream_t stream) {
  const float* H = (const float*)d_in[0];   // [B*S, 4096]
  const float* W = (const float*)d_in[1];   // [4096, 64]
  const float* G = (const float*)d_in[2];   // [64]
  float* out = (float*)d_out;               // 3 x [B*S, 64] concatenated
  __bf16* Wp = (__bf16*)d_ws;               // 512 KB packed (unnormalized) W
  float* partial = (float*)((char*)d_ws + 512 * 1024);  // 64 blocks x 64 cols

  int rows = in_sizes[0] / HDIM;            // 16384
  size_t third = (size_t)out_size / 3;      // 1048576

  pack_w_kernel<<<64, 256, 0, stream>>>(W, Wp, partial);
  gate_main_kernel<<<rows / 64, 512, 0, stream>>>(H, Wp, G, partial, out, third);
}

// Round 10
// 57.878 us; speedup vs baseline: 1.2143x; 1.2143x over previous
//
#include <hip/hip_runtime.h>
#include <hip/hip_bf16.h>

typedef __bf16 bf16x8 __attribute__((ext_vector_type(8)));
typedef float f32x4 __attribute__((ext_vector_type(4)));
typedef unsigned int u32;

#define HDIM 4096
#define EDIM 64
#define KBLK 128        // 4096 / 32
#define NW 8            // waves per block = K-split factor
#define KBW (KBLK/NW)   // 16 kb-steps per wave
#define NRG 4           // row-groups per wave (64 rows per block)

// ---------------------------------------------------------------------------
// Kernel 1: coalesced repack of W into MFMA B-frag layout (UNnormalized bf16)
// + per-block per-column sum-of-squares partials (fp32).
// ---------------------------------------------------------------------------
__global__ __launch_bounds__(256) void pack_w_kernel(const float* __restrict__ W,
                                                     __bf16* __restrict__ Wp,
                                                     float* __restrict__ partial) {
  const int b = blockIdx.x;        // 64 blocks x 64 rows of W
  const int t = threadIdx.x;
  const int e = t & 63;
  const int nt = e >> 4, col = e & 15;
  __shared__ float red[256];
  float s = 0.f;
  const int base = b * 64 * 64;
#pragma unroll
  for (int i = 0; i < 16; ++i) {
    int flat = base + i * 256 + t;         // coalesced
    float v = W[flat];
    s = fmaf(v, v, s);
    int r = flat >> 6;                     // k index
    int kb = r >> 5, g = (r >> 3) & 3, j = r & 7;
    Wp[(size_t)((nt * KBLK + kb) * 64 + col + 16 * g) * 8 + j] = (__bf16)v;
  }
  red[t] = s;
  __syncthreads();
  if (t < 64)
    partial[b * 64 + t] = red[t] + red[t + 64] + red[t + 128] + red[t + 192];
}

// direct global->LDS DMA, 16 B per lane, dest = wave-uniform base + lane*16
__device__ __forceinline__ void gload16(const float* g, char* l) {
  __builtin_amdgcn_global_load_lds(
      (const __attribute__((address_space(1))) u32*)g,
      (__attribute__((address_space(3))) u32*)l, 16, 0, 0);
}

// ---------------------------------------------------------------------------
// Kernel 2: fused norm_h @ (Wp * invw) + epilogue.
// R6 tiling (64 rows/block, grid 256 = 1 block/CU, 8-wave K-split x8, no
// main-loop barriers) with the A path moved to global_load_lds DMA:
//   global (pre-swizzled per-lane src, full 64B lines) -> linear LDS dest
//   -> XOR-swizzled ds_read_b128 frags (2 lanes/slot = conflict-free).
// Explicit counted s_waitcnt vmcnt(12) (never 0): next-step DMA (8) + B
// loads (4) stay in flight across every step.
// Stage swizzle: lds[row*128 + (chunk*16 ^ ((row&7)<<4))] = H[row][chunk]
//   achieved with linear dest by lane l fetching chunk (l&7)^(l>>3).
// A-frag read: lane(m,g) rg,s -> byte (rg*16+m)*128 + ((g*32+s*16)^((m&7)<<4)).
// C/D layout (m89): lane l, reg r -> row (l>>4)*4+r, col l&15.
// Stage buffers (128 KB) alias the epilogue lds_acc, barrier-separated.
// ---------------------------------------------------------------------------
__global__ __launch_bounds__(512, 1) void gate_main_kernel(
    const float* __restrict__ H, const __bf16* __restrict__ Wp,
    const float* __restrict__ G, const float* __restrict__ partial,
    float* __restrict__ out, size_t third) {
  const int lane = threadIdx.x & 63;
  const int w = threadIdx.x >> 6;        // wave id = K-slice id, 0..7
  const int m = lane & 15;
  const int g = lane >> 4;
  const int row0 = blockIdx.x * 64;

  __shared__ __align__(16) char smem[NW * 16 * 1024];  // 128 KB: stage / acc
  __shared__ float lds_ssq[NW][64];
  __shared__ float lds_invw[64];

  // W-column inv-norms from pack partials (tiny, once per block)
  if (threadIdx.x < 64) {
    float cs = 0.f;
#pragma unroll 8
    for (int i = 0; i < 64; ++i) cs += partial[i * 64 + threadIdx.x];
    lds_invw[threadIdx.x] = 1.0f / fmaxf(sqrtf(cs), 1e-12f);
  }
  __syncthreads();   // smem about to be written by DMA; invw done

  const int kb0 = w * KBW;
  char* sb = smem + w * 16384;           // wave-private 2 x 8 KB buffers

  // pre-swizzled per-lane global source (see header comment)
  const int lr = lane >> 3;              // row-within-8
  const int lc = (lane & 7) ^ lr;        // swizzled 16B chunk
  const float* hbase = H + (size_t)(row0 + lr) * HDIM + kb0 * 32 + lc * 4;

  // swizzled frag-read byte offsets
  const int sw = (m & 7) << 4;
  const int rb0 = m * 128 + ((g * 32) ^ sw);
  const int rb1 = m * 128 + ((g * 32 + 16) ^ sw);

  const bf16x8* bbase = reinterpret_cast<const bf16x8*>(Wp) + lane;

  f32x4 acc[NRG][4] = {};
  float ssqa[NRG], ssqb[NRG];
#pragma unroll
  for (int rg = 0; rg < NRG; ++rg) { ssqa[rg] = 0.f; ssqb[rg] = 0.f; }

#define STAGE(buf, I) { _Pragma("unroll")                                      \
    for (int c = 0; c < 8; ++c)                                                \
      gload16(hbase + (size_t)c * 8 * HDIM + (size_t)(I) * 32, (buf) + c * 1024); }

  STAGE(sb, 0);   // prologue: buf0 <- kb-step 0

  for (int i = 0; i < KBW; ++i) {
    char* cur = sb + (i & 1) * 8192;
    if (i + 1 < KBW) STAGE(sb + ((i + 1) & 1) * 8192, i + 1);

    bf16x8 bfr[4];
#pragma unroll
    for (int nt = 0; nt < 4; ++nt)
      bfr[nt] = bbase[(size_t)(nt * KBLK + kb0 + i) * 64];

    // wait for cur's 8 DMA writes; leave next-stage(8) + B(4) in flight
    if (i + 1 < KBW) asm volatile("s_waitcnt vmcnt(12)" ::: "memory");
    else             asm volatile("s_waitcnt vmcnt(4)" ::: "memory");
    __builtin_amdgcn_sched_barrier(0);

#pragma unroll
    for (int rg = 0; rg < NRG; ++rg) {
      f32x4 x0 = *(const f32x4*)(cur + rg * 2048 + rb0);
      f32x4 x1 = *(const f32x4*)(cur + rg * 2048 + rb1);

      bf16x8 af;
      af[0] = (__bf16)x0[0]; af[1] = (__bf16)x0[1];
      af[2] = (__bf16)x0[2]; af[3] = (__bf16)x0[3];
      af[4] = (__bf16)x1[0]; af[5] = (__bf16)x1[1];
      af[6] = (__bf16)x1[2]; af[7] = (__bf16)x1[3];

      ssqa[rg] = fmaf(x0[0], x0[0], ssqa[rg]);
      ssqb[rg] = fmaf(x0[1], x0[1], ssqb[rg]);
      ssqa[rg] = fmaf(x0[2], x0[2], ssqa[rg]);
      ssqb[rg] = fmaf(x0[3], x0[3], ssqb[rg]);
      ssqa[rg] = fmaf(x1[0], x1[0], ssqa[rg]);
      ssqb[rg] = fmaf(x1[1], x1[1], ssqb[rg]);
      ssqa[rg] = fmaf(x1[2], x1[2], ssqa[rg]);
      ssqb[rg] = fmaf(x1[3], x1[3], ssqb[rg]);

#pragma unroll
      for (int nt = 0; nt < 4; ++nt)
        acc[rg][nt] = __builtin_amdgcn_mfma_f32_16x16x32_bf16(af, bfr[nt], acc[rg][nt], 0, 0, 0);
    }
  }
#undef STAGE

  __syncthreads();   // all waves done with stage buffers; reuse as lds_acc
  float (*lds_acc)[4][4][NW][64] = (float (*)[4][4][NW][64])smem;

#pragma unroll
  for (int rg = 0; rg < NRG; ++rg) {
    float ssq = ssqa[rg] + ssqb[rg];
    ssq += __shfl_xor(ssq, 16, 64);
    ssq += __shfl_xor(ssq, 32, 64);
    if (g == 0) lds_ssq[w][rg * 16 + m] = ssq;
#pragma unroll
    for (int nt = 0; nt < 4; ++nt)
#pragma unroll
      for (int r = 0; r < 4; ++r)
        lds_acc[rg][nt][r][w][lane] = acc[rg][nt][r];
  }
  __syncthreads();

  // Epilogue: lane = output column e; wave w handles rows {8w .. 8w+7},
  // full 256-B contiguous stores per output tensor.
  {
    const int e = lane;
    const float invw = lds_invw[e];
    const float sg = 1.0f / (1.0f + __expf(-G[e]));
    const int nt = e >> 4;
#pragma unroll
    for (int rr = 0; rr < 8; ++rr) {
      const int R = w * 8 + rr;
      const int rg = R >> 4;
      const int r = R & 3;
      const int lsrc = (((R >> 2) & 3) << 4) | (e & 15);
      float st = 0.f, a = 0.f;
#pragma unroll
      for (int s = 0; s < NW; ++s) {
        st += lds_ssq[s][R];
        a += lds_acc[rg][nt][r][s][lsrc];
      }
      float invh = 1.0f / fmaxf(sqrtf(st), 1e-12f);
      float raw = a * invh * invw;
      float sig = 1.0f / (1.0f + __expf(-raw));
      size_t idx = (size_t)(row0 + R) * EDIM + e;
      out[idx] = raw;
      out[idx + third] = sig;
      out[idx + 2 * third] = fmaxf(sig - sg, 0.0f);
    }
  }
}

extern "C" void kernel_launch(void* const* d_in, const int* in_sizes, int n_in,
                              void* d_out, int out_size, void* d_ws, size_t ws_size,
                              hipStream_t stream) {
  const float* H = (const float*)d_in[0];   // [B*S, 4096]
  const float* W = (const float*)d_in[1];   // [4096, 64]
  const float* G = (const float*)d_in[2];   // [64]
  float* out = (float*)d_out;               // 3 x [B*S, 64] concatenated
  __bf16* Wp = (__bf16*)d_ws;               // 512 KB packed (unnormalized) W
  float* partial = (float*)((char*)d_ws + 512 * 1024);  // 64 blocks x 64 cols

  int rows = in_sizes[0] / HDIM;            // 16384
  size_t third = (size_t)out_size / 3;      // 1048576

  pack_w_kernel<<<64, 256, 0, stream>>>(W, Wp, partial);
  gate_main_kernel<<<rows / 64, 512, 0, stream>>>(H, Wp, G, partial, out, third);
}